// Round 8
// baseline (108.655 us; speedup 1.0000x reference)
//
#include <hip/hip_runtime.h>
#include <hip/hip_bf16.h>

typedef __attribute__((ext_vector_type(4))) float f32x4;
typedef __attribute__((ext_vector_type(8))) short bf16x8;

static __device__ __forceinline__ unsigned short f2bf(float f) {
  union { float f; unsigned u; } v;
  v.f = f;
  unsigned r = v.u + 0x7FFFu + ((v.u >> 16) & 1u);
  return (unsigned short)(r >> 16);
}

static __device__ __forceinline__ unsigned cvt_pk_bf16(float lo, float hi) {
  unsigned r;
  asm("v_cvt_pk_bf16_f32 %0, %1, %2" : "=v"(r) : "v"(lo), "v"(hi));
  return r;
}

static __device__ __forceinline__ void gload16(const void* g, void* lds) {
  __builtin_amdgcn_global_load_lds(
      (const __attribute__((address_space(1))) unsigned int*)g,
      (__attribute__((address_space(3))) unsigned int*)lds, 16, 0, 0);
}

// ---------------- fused prep: cast x, transpose+cast w_qkv / w_out ----------------
__global__ __launch_bounds__(256) void prep_kernel(
    const float* __restrict__ x, const float* __restrict__ w_qkv,
    const float* __restrict__ w_out, unsigned short* __restrict__ xb,
    unsigned short* __restrict__ wqkvT, unsigned short* __restrict__ woT) {
  __shared__ float tile[32][33];
  const int bid = blockIdx.x, tid = threadIdx.x;
  if (bid < 4096) {  // cast x -> bf16
    int i = bid * 256 + tid;
    float4 v = reinterpret_cast<const float4*>(x)[i];
    ushort4 o;
    o.x = f2bf(v.x); o.y = f2bf(v.y); o.z = f2bf(v.z); o.w = f2bf(v.w);
    reinterpret_cast<ushort4*>(xb)[i] = o;
    return;
  }
  const float* src; unsigned short* dst; int c0, r0, C;
  if (bid < 7168) {
    int t = bid - 4096;
    src = w_qkv; dst = wqkvT; C = 3072;
    c0 = (t % 96) * 32; r0 = (t / 96) * 32;
  } else {
    int t = bid - 7168;
    src = w_out; dst = woT; C = 1024;
    c0 = (t & 31) * 32; r0 = (t >> 5) * 32;
  }
  int tx = tid & 31, ty = tid >> 5;
#pragma unroll
  for (int i = 0; i < 32; i += 8)
    tile[ty + i][tx] = src[(size_t)(r0 + ty + i) * C + c0 + tx];
  __syncthreads();
#pragma unroll
  for (int i = 0; i < 32; i += 8)
    dst[(size_t)(c0 + ty + i) * 1024 + r0 + tx] = f2bf(tile[tx][ty + i]);
}

// ============== GEMM1: 8-phase 256x256, BK=64, 512 thr, 128KB LDS ==============
// A: xb [4096][1024] bf16. Bt: wqkvT [3072][1024] bf16. Scatter epilogue -> Q/K/V.
// Phase p (0..7): consume buf=p>>2, quadrant qd=p&3. Stage schedule (freed-region):
//   p0: A(kt+1).h0->Abuf1  p1: A(kt+1).h1  p2: B(kt+2).h0->Bbuf0  p3: B(kt+2).h1
//   p4: A(kt+2).h0->Abuf0  p5: A(kt+2).h1  p6: B(kt+3).h0->Bbuf1  p7: B(kt+3).h1
// vmcnt ledger (2 ops/half-tile/thread): entering p0 outstanding<=4 {B(kt+1)};
//   p3 after stage: <=12; vmcnt(4) -> done: B(kt+1)[p4 needs], A(kt+1)[p4 needs];
//   p7: <=12; vmcnt(4) -> done: B(kt+2),A(kt+2)[next p0 needs]; left B(kt+3). QED.
// Tail (it==7): stages of kt+2/kt+3 skipped; p3 uses vmcnt(0) so A(15) is waited.
__global__ __launch_bounds__(512, 2) void gemm_qkv_8ph(
    const unsigned short* __restrict__ A,
    const unsigned short* __restrict__ Bt,
    const float* __restrict__ bias,
    unsigned short* __restrict__ q_out,
    unsigned short* __restrict__ k_out,
    unsigned short* __restrict__ v_out) {
  __shared__ __align__(16) char AsB[2 * 32768];  // [buf][half 16KB][row 128B swz]
  __shared__ __align__(16) char BsB[2 * 32768];

  const int tid = threadIdx.x;
  const int lane = tid & 63, wid = tid >> 6;
  const int l15 = lane & 15, g = lane >> 4;
  const int wm = wid >> 2, wn = wid & 3;  // 2M x 4N waves

  // bijective XCD decode: each XCD gets 24 consecutive lin -> 1-2 B-col panels
  const int wg = blockIdx.x;
  const int lin = (wg & 7) * 24 + (wg >> 3);
  const int bx = lin >> 4, by = lin & 15;  // 12 x 16
  const int n0 = bx * 256, m0 = by * 256;

  const int srow = tid >> 3;          // 0..63 (pass0), +64 pass1
  const int scb = (tid & 7) << 4;     // byte col in 128B row
  const int sswz = scb ^ ((srow & 7) << 4);  // (row&7) invariant under +64

  auto stageHalf = [&](const unsigned short* mat, int rowbase, int kt, char* region) {
#pragma unroll
    for (int i = 0; i < 2; ++i) {
      gload16((const char*)mat + ((size_t)(rowbase + srow + i * 64) * 1024 + kt * 64) * 2 + sswz,
              region + (wid * 64 + i * 512) * 16);
    }
  };
  auto rdA = [&](const char* Ab, int mi, int ks) -> bf16x8 {
    int r = mi * 16 + l15;  // 0..127 within wave's half (wm)
    int c = (ks * 64 + g * 16) ^ ((r & 7) << 4);
    return *reinterpret_cast<const bf16x8*>(Ab + wm * 16384 + r * 128 + c);
  };
  auto rdB = [&](const char* Bb, int ni, int ks) -> bf16x8 {
    int rr = wn * 64 + ni * 16 + l15;  // 0..255
    int c = (ks * 64 + g * 16) ^ ((rr & 7) << 4);
    return *reinterpret_cast<const bf16x8*>(Bb + (rr >> 7) * 16384 + (rr & 127) * 128 + c);
  };

  f32x4 acc[8][4] = {};

  // prologue: A0(h0,h1), B0(h0,h1), B1(h0,h1) = 12 ops; wait first 8 (A0,B0)
  stageHalf(A, m0, 0, AsB);
  stageHalf(A, m0 + 128, 0, AsB + 16384);
  stageHalf(Bt, n0, 0, BsB);
  stageHalf(Bt, n0 + 128, 0, BsB + 16384);
  stageHalf(Bt, n0, 1, BsB + 32768);
  stageHalf(Bt, n0 + 128, 1, BsB + 32768 + 16384);
  asm volatile("s_waitcnt vmcnt(4)" ::: "memory");
  __builtin_amdgcn_s_barrier();
  __builtin_amdgcn_sched_barrier(0);

  for (int it = 0; it < 8; ++it) {
    const int kt0 = it * 2;
    bf16x8 bfr[4][2];
#pragma unroll
    for (int ph = 0; ph < 8; ++ph) {
      const int buf = ph >> 2, qd = ph & 3;
      const char* Ab = AsB + buf * 32768;
      const char* Bb = BsB + buf * 32768;
      if (qd == 0) {  // K-tile entry: read all B frags (held in regs through 4 phases)
#pragma unroll
        for (int ni = 0; ni < 4; ++ni)
#pragma unroll
          for (int ks = 0; ks < 2; ++ks) bfr[ni][ks] = rdB(Bb, ni, ks);
      }
      bf16x8 af[2][2];
#pragma unroll
      for (int msub = 0; msub < 2; ++msub)
#pragma unroll
        for (int ks = 0; ks < 2; ++ks) af[msub][ks] = rdA(Ab, qd * 2 + msub, ks);

      // stage one half-tile (see schedule above)
      if (ph == 0) stageHalf(A, m0, kt0 + 1, AsB + 32768);
      else if (ph == 1) stageHalf(A, m0 + 128, kt0 + 1, AsB + 32768 + 16384);
      else if (it < 7) {
        if (ph == 2) stageHalf(Bt, n0, kt0 + 2, BsB);
        else if (ph == 3) stageHalf(Bt, n0 + 128, kt0 + 2, BsB + 16384);
        else if (ph == 4) stageHalf(A, m0, kt0 + 2, AsB);
        else if (ph == 5) stageHalf(A, m0 + 128, kt0 + 2, AsB + 16384);
        else if (ph == 6) stageHalf(Bt, n0, kt0 + 3, BsB + 32768);
        else stageHalf(Bt, n0 + 128, kt0 + 3, BsB + 32768 + 16384);
      }
      if (ph == 3) {
        if (it == 7) { asm volatile("s_waitcnt vmcnt(0)" ::: "memory"); }
        else         { asm volatile("s_waitcnt vmcnt(4)" ::: "memory"); }
      } else if (ph == 7 && it < 7) {
        asm volatile("s_waitcnt vmcnt(4)" ::: "memory");
      }
      __builtin_amdgcn_s_barrier();
      __builtin_amdgcn_sched_barrier(0);

      __builtin_amdgcn_s_setprio(1);
#pragma unroll
      for (int ks = 0; ks < 2; ++ks)
#pragma unroll
        for (int msub = 0; msub < 2; ++msub)
#pragma unroll
          for (int ni = 0; ni < 4; ++ni)
            acc[qd * 2 + msub][ni] = __builtin_amdgcn_mfma_f32_16x16x32_bf16(
                af[msub][ks], bfr[ni][ks], acc[qd * 2 + msub][ni], 0, 0, 0);
      __builtin_amdgcn_s_setprio(0);
      __builtin_amdgcn_s_barrier();
      __builtin_amdgcn_sched_barrier(0);
    }
  }

  // scatter epilogue -> Q/K/V [BH][2048][64] (Q pre-scaled by 0.125*log2e)
  const int which = n0 >> 10;  // block-uniform (256 | 1024)
  unsigned short* dst = (which == 0) ? q_out : (which == 1) ? k_out : v_out;
  const float oscale = (which == 0) ? 0.125f * 1.44269504f : 1.0f;
#pragma unroll
  for (int ni = 0; ni < 4; ++ni) {
    int col = n0 + wn * 64 + ni * 16 + l15;
    int c = col & 1023;
    int h = c >> 6, d = c & 63;
    float bv = bias[col];
#pragma unroll
    for (int mi = 0; mi < 8; ++mi) {
#pragma unroll
      for (int r = 0; r < 4; ++r) {
        int rowg = m0 + wm * 128 + mi * 16 + g * 4 + r;
        int bb = rowg >> 11, tt = rowg & 2047;
        dst[((bb * 16 + h) * 2048 + tt) * 64 + d] = f2bf((acc[mi][ni][r] + bv) * oscale);
      }
    }
  }
}

// ---------------- bf16 GEMM2, 128x64 tile, BK=32, 2-phase prefetch ----------------
__global__ __launch_bounds__(256, 2) void gemm_out(
    const unsigned short* __restrict__ A,
    const unsigned short* __restrict__ Bt,
    const float* __restrict__ bias,
    float* __restrict__ f_out) {
  constexpr int BN = 64, NB2 = 2, NBL = 1;
  __shared__ __align__(16) unsigned short As[2][128 * 32];
  __shared__ __align__(16) unsigned short Bs[2][BN * 32];

  const int tid = threadIdx.x;
  const int wid = tid >> 6, lane = tid & 63;
  const int l15 = lane & 15, g = lane >> 4;
  const int wm = wid >> 1, wn = wid & 1;
  const int n0 = blockIdx.x * BN, m0 = blockIdx.y * 128;

  f32x4 acc[4][NB2] = {};

  auto stage = [&](int k0, int bsel) {
#pragma unroll
    for (int i = 0; i < 2; ++i) {
      int t = tid + i * 256;
      int row = t >> 2, c8 = (t & 3) << 3;
      gload16(A + (size_t)(m0 + row) * 1024 + k0 + c8, &As[bsel][(i * 256 + wid * 64) * 8]);
    }
#pragma unroll
    for (int i = 0; i < NBL; ++i) {
      int t = tid + i * 256;
      int row = t >> 2, c8 = (t & 3) << 3;
      gload16(Bt + (size_t)(n0 + row) * 1024 + k0 + c8, &Bs[bsel][(i * 256 + wid * 64) * 8]);
    }
  };

  stage(0, 0);
  __syncthreads();
  for (int ks = 0; ks < 32; ++ks) {
    const int cur = ks & 1;
    if (ks + 1 < 32) stage((ks + 1) * 32, cur ^ 1);
    bf16x8 a[4], b[NB2];
#pragma unroll
    for (int mi = 0; mi < 4; ++mi)
      a[mi] = *reinterpret_cast<const bf16x8*>(&As[cur][(wm * 64 + mi * 16 + l15) * 32 + g * 8]);
#pragma unroll
    for (int ni = 0; ni < NB2; ++ni)
      b[ni] = *reinterpret_cast<const bf16x8*>(&Bs[cur][(wn * (BN / 2) + ni * 16 + l15) * 32 + g * 8]);
    __builtin_amdgcn_s_setprio(1);
#pragma unroll
    for (int mi = 0; mi < 4; ++mi)
#pragma unroll
      for (int ni = 0; ni < NB2; ++ni)
        acc[mi][ni] = __builtin_amdgcn_mfma_f32_16x16x32_bf16(a[mi], b[ni], acc[mi][ni], 0, 0, 0);
    __builtin_amdgcn_s_setprio(0);
    __syncthreads();
  }

#pragma unroll
  for (int ni = 0; ni < NB2; ++ni) {
    int col = n0 + wn * (BN / 2) + ni * 16 + l15;
    float bv = bias[col];
#pragma unroll
    for (int mi = 0; mi < 4; ++mi)
#pragma unroll
      for (int r = 0; r < 4; ++r) {
        int rowg = m0 + wm * 64 + mi * 16 + g * 4 + r;
        f_out[(size_t)rowg * 1024 + col] = acc[mi][ni][r] + bv;
      }
  }
}

// ---------------- causal flash attention: 4 blocks/CU (40KB LDS) ----------------
#define KS_SZ (64 * 64)
#define VT_SZ (64 * 64)

__device__ __forceinline__ void attn_stage_K(const unsigned short* __restrict__ Kb,
                                             int k0, unsigned short* KsBuf,
                                             int tid, int wid) {
#pragma unroll
  for (int i = 0; i < 2; ++i) {
    int t = tid + i * 256;
    int row = t >> 3;
    int cb = (t & 7) << 4;
    int src = cb ^ ((row & 7) << 4);  // pre-swizzled global source (rule 21)
    gload16((const char*)Kb + (size_t)(k0 + row) * 128 + src,
            (char*)KsBuf + (i * 256 + wid * 64) * 16);
  }
}

__device__ __forceinline__ void write_vt(unsigned short* VtBuf, int kvL, int d8,
                                         uint4 v0, uint4 v1) {
  char* base = (char*)VtBuf + (size_t)d8 * 128;
  const int c = kvL * 2;
  unsigned lo, hi;
  lo = __builtin_amdgcn_perm(v1.x, v0.x, 0x05040100u);
  hi = __builtin_amdgcn_perm(v1.x, v0.x, 0x07060302u);
  *reinterpret_cast<unsigned*>(base + 0 * 128 + (c ^ (0 << 4))) = lo;
  *reinterpret_cast<unsigned*>(base + 1 * 128 + (c ^ (1 << 4))) = hi;
  lo = __builtin_amdgcn_perm(v1.y, v0.y, 0x05040100u);
  hi = __builtin_amdgcn_perm(v1.y, v0.y, 0x07060302u);
  *reinterpret_cast<unsigned*>(base + 2 * 128 + (c ^ (2 << 4))) = lo;
  *reinterpret_cast<unsigned*>(base + 3 * 128 + (c ^ (3 << 4))) = hi;
  lo = __builtin_amdgcn_perm(v1.z, v0.z, 0x05040100u);
  hi = __builtin_amdgcn_perm(v1.z, v0.z, 0x07060302u);
  *reinterpret_cast<unsigned*>(base + 4 * 128 + (c ^ (4 << 4))) = lo;
  *reinterpret_cast<unsigned*>(base + 5 * 128 + (c ^ (5 << 4))) = hi;
  lo = __builtin_amdgcn_perm(v1.w, v0.w, 0x05040100u);
  hi = __builtin_amdgcn_perm(v1.w, v0.w, 0x07060302u);
  *reinterpret_cast<unsigned*>(base + 6 * 128 + (c ^ (6 << 4))) = lo;
  *reinterpret_cast<unsigned*>(base + 7 * 128 + (c ^ (7 << 4))) = hi;
}

__global__ __launch_bounds__(256, 4) void attn_fwd(
    const unsigned short* __restrict__ Q,
    const unsigned short* __restrict__ K,
    const unsigned short* __restrict__ V,
    unsigned short* __restrict__ O) {
  __shared__ __align__(16) unsigned short Ks[2 * KS_SZ];
  __shared__ __align__(16) unsigned short Vt[2 * VT_SZ];
  __shared__ __align__(16) unsigned short Ps[64 * 64];

  const int tid = threadIdx.x;
  const int wid = tid >> 6;
  const int l15 = tid & 15;
  const int g = (tid & 63) >> 4;

  const int lin = blockIdx.x;
  const int bh = lin & 31;
  const int o = lin >> 5, oq = o & 7, os = o >> 3;
  const int qt = (os == 0) ? 31 - oq : (os == 1) ? 16 + oq : (os == 2) ? 15 - oq : oq;
  const int b = bh >> 4, h = bh & 15;
  const int q0 = qt << 6, nt = qt + 1;

  const unsigned short* Qb = Q + (size_t)bh * 2048 * 64;
  const unsigned short* Kb = K + (size_t)bh * 2048 * 64;
  const unsigned short* Vb = V + (size_t)bh * 2048 * 64;

  bf16x8 qf[2];
  {
    const unsigned short* qrow_p = Qb + (size_t)(q0 + wid * 16 + l15) * 64;
    qf[0] = *reinterpret_cast<const bf16x8*>(qrow_p + g * 8);
    qf[1] = *reinterpret_cast<const bf16x8*>(qrow_p + 32 + g * 8);
  }

  float m_run = -1e30f;
  float l_run = 0.0f;
  f32x4 ot[4] = {};
  const int qg = q0 + wid * 16 + l15;
  const int kvL = (tid & 31) * 2, d8 = (tid >> 5) * 8;
  const int qrow = wid * 16 + l15;
  const int sP = (qrow & 7) << 4;

  attn_stage_K(Kb, 0, Ks, tid, wid);
  {
    const uint4* vp = reinterpret_cast<const uint4*>(Vb + (size_t)kvL * 64 + d8);
    write_vt(Vt, kvL, d8, vp[0], vp[8]);
  }
  __syncthreads();

  for (int t = 0; t < nt; ++t) {
    const unsigned short* KsC = Ks + (t & 1) * KS_SZ;
    const unsigned short* VtC = Vt + (t & 1) * VT_SZ;
    uint4 va, vb;
    const bool pf = (t + 1 < nt);
    if (pf) {
      attn_stage_K(Kb, (t + 1) << 6, Ks + ((t + 1) & 1) * KS_SZ, tid, wid);
      const uint4* vp = reinterpret_cast<const uint4*>(
          Vb + (size_t)(((t + 1) << 6) + kvL) * 64 + d8);
      va = vp[0];
      vb = vp[8];
    }

    f32x4 s[4] = {};
    __builtin_amdgcn_s_setprio(1);
#pragma unroll
    for (int kk = 0; kk < 2; ++kk)
#pragma unroll
      for (int mi = 0; mi < 4; ++mi) {
        int row = mi * 16 + l15;
        int cb = (kk * 64 + g * 16) ^ ((row & 7) << 4);
        bf16x8 kf = *reinterpret_cast<const bf16x8*>((const char*)KsC + row * 128 + cb);
        s[mi] = __builtin_amdgcn_mfma_f32_16x16x32_bf16(kf, qf[kk], s[mi], 0, 0, 0);
      }
    __builtin_amdgcn_s_setprio(0);

    if (t == nt - 1) {
      const int k0 = t << 6;
#pragma unroll
      for (int mi = 0; mi < 4; ++mi)
#pragma unroll
        for (int r = 0; r < 4; ++r) {
          int kvg = k0 + mi * 16 + g * 4 + r;
          s[mi][r] = (kvg <= qg) ? s[mi][r] : -1e30f;
        }
    }

    float pmax = -1e30f;
#pragma unroll
    for (int mi = 0; mi < 4; ++mi)
#pragma unroll
      for (int r = 0; r < 4; ++r) pmax = fmaxf(pmax, s[mi][r]);

    if (!__all(pmax <= m_run + 8.0f)) {
      float tmax = fmaxf(pmax, __shfl_xor(pmax, 16));
      tmax = fmaxf(tmax, __shfl_xor(tmax, 32));
      float m_new = fmaxf(m_run, tmax);
      float corr = __builtin_amdgcn_exp2f(m_run - m_new);
      l_run *= corr;
#pragma unroll
      for (int mi = 0; mi < 4; ++mi)
#pragma unroll
        for (int r = 0; r < 4; ++r) ot[mi][r] *= corr;
      m_run = m_new;
    }

    float tsum = 0.f;
#pragma unroll
    for (int mi = 0; mi < 4; ++mi) {
      float p0 = __builtin_amdgcn_exp2f(s[mi][0] - m_run);
      float p1 = __builtin_amdgcn_exp2f(s[mi][1] - m_run);
      float p2 = __builtin_amdgcn_exp2f(s[mi][2] - m_run);
      float p3 = __builtin_amdgcn_exp2f(s[mi][3] - m_run);
      tsum += (p0 + p1) + (p2 + p3);
      uint2 pk;
      pk.x = cvt_pk_bf16(p0, p1);
      pk.y = cvt_pk_bf16(p2, p3);
      *reinterpret_cast<uint2*>((char*)Ps + qrow * 128 + ((mi * 32 + g * 8) ^ sP)) = pk;
    }
    l_run += tsum;

    __builtin_amdgcn_s_setprio(1);
#pragma unroll
    for (int kk = 0; kk < 2; ++kk) {
      bf16x8 pfr = *reinterpret_cast<const bf16x8*>(
          (const char*)Ps + qrow * 128 + ((kk * 64 + g * 16) ^ sP));
#pragma unroll
      for (int mi = 0; mi < 4; ++mi) {
        int row = mi * 16 + l15;
        bf16x8 vf = *reinterpret_cast<const bf16x8*>(
            (const char*)VtC + row * 128 + ((kk * 64 + g * 16) ^ ((row & 7) << 4)));
        ot[mi] = __builtin_amdgcn_mfma_f32_16x16x32_bf16(vf, pfr, ot[mi], 0, 0, 0);
      }
    }
    __builtin_amdgcn_s_setprio(0);

    if (pf) write_vt(Vt + ((t + 1) & 1) * VT_SZ, kvL, d8, va, vb);
    __syncthreads();
  }

  float l_tot = l_run + __shfl_xor(l_run, 16);
  l_tot += __shfl_xor(l_tot, 32);
  float inv_l = 1.0f / l_tot;

#pragma unroll
  for (int mi = 0; mi < 4; ++mi) {
    uint2 pk;
    pk.x = cvt_pk_bf16(ot[mi][0] * inv_l, ot[mi][1] * inv_l);
    pk.y = cvt_pk_bf16(ot[mi][2] * inv_l, ot[mi][3] * inv_l);
    int b0 = (mi * 32 + g * 8) ^ sP;
    *reinterpret_cast<uint2*>((char*)Ks + qrow * 128 + b0) = pk;
  }
  __syncthreads();
#pragma unroll
  for (int i = 0; i < 2; ++i) {
    int t = tid + i * 256;
    int row = t >> 3;
    int cb = (t & 7) << 4;
    int sw = cb ^ ((row & 7) << 4);
    bf16x8 vv = *reinterpret_cast<const bf16x8*>((const char*)Ks + row * 128 + sw);
    *reinterpret_cast<bf16x8*>(O + ((size_t)(b * 2048 + q0 + row)) * 1024 + h * 64 + (cb >> 1)) = vv;
  }
}

// ---------------- launch ----------------
extern "C" void kernel_launch(void* const* d_in, const int* in_sizes, int n_in,
                              void* d_out, int out_size, void* d_ws, size_t ws_size,
                              hipStream_t stream) {
  const float* x = (const float*)d_in[0];
  const float* w_qkv = (const float*)d_in[1];
  const float* b_qkv = (const float*)d_in[2];
  const float* w_out = (const float*)d_in[3];
  const float* b_out = (const float*)d_in[4];
  float* out = (float*)d_out;
  char* ws = (char*)d_ws;

  unsigned short* xb    = (unsigned short*)d_out;            // dead before GEMM2 writes
  unsigned short* wqkvT = (unsigned short*)(ws);             //  6 MB
  unsigned short* woT   = (unsigned short*)(ws + 6291456);   //  2 MB
  unsigned short* q_buf = (unsigned short*)(ws + 8388608);   //  8 MB
  unsigned short* k_buf = (unsigned short*)(ws + 16777216);  //  8 MB
  unsigned short* v_buf = (unsigned short*)(ws + 25165824);  //  8 MB
  unsigned short* aout  = (unsigned short*)(ws + 33554432);  //  8 MB -> 40 MB total

  prep_kernel<<<dim3(8192), dim3(256), 0, stream>>>(x, w_qkv, w_out, xb, wqkvT, woT);

  gemm_qkv_8ph<<<dim3(192), dim3(512), 0, stream>>>(
      xb, wqkvT, b_qkv, q_buf, k_buf, v_buf);

  attn_fwd<<<dim3(1024), dim3(256), 0, stream>>>(q_buf, k_buf, v_buf, aout);

  gemm_out<<<dim3(16, 32), dim3(256), 0, stream>>>(aout, woT, b_out, out);
}